// Round 1
// baseline (443.729 us; speedup 1.0000x reference)
//
#include <hip/hip_runtime.h>
#include <hip/hip_bf16.h>

#define NN 32768
#define NE 524288
#define HID 128

typedef unsigned short u16;
typedef __bf16 bf16x8 __attribute__((ext_vector_type(8)));
typedef float f32x4 __attribute__((ext_vector_type(4)));

__device__ __forceinline__ u16 f2bf(float f) {
  union { float f; unsigned u; } v; v.f = f;
  return (u16)((v.u + 0x7fffu + ((v.u >> 16) & 1u)) >> 16);  // RNE
}
__device__ __forceinline__ float silu_f(float v) { return v / (1.f + __expf(-v)); }

// ---------------------------------------------------------------- prep ----
// zero sums/counts, x -> bf16, weights -> bf16 transposed (col-major: wT[col][k])
__global__ __launch_bounds__(256) void prep_k(
    const float* __restrict__ x, const float* __restrict__ w1,
    const float* __restrict__ w2, const float* __restrict__ wu1,
    const float* __restrict__ wu2,
    u16* __restrict__ xb, u16* __restrict__ w1T, u16* __restrict__ w2T,
    u16* __restrict__ wu1T, u16* __restrict__ wu2T,
    float* __restrict__ sums, float* __restrict__ cnts)
{
  int i = blockIdx.x * 256 + threadIdx.x;   // grid covers exactly NN*HID
  sums[i] = 0.f;
  xb[i] = f2bf(x[i]);
  if (i < NN) cnts[i] = 0.f;
  if (i < 384 * 128) { int c = i / 384, k = i - c * 384; w1T[i]  = f2bf(w1[k * 128 + c]); }
  if (i < 128 * 128) { int c = i >> 7,  k = i & 127;     w2T[i]  = f2bf(w2[k * 128 + c]); }
  if (i < 256 * 128) { int c = i >> 7,  k = i & 127;     wu1T[i] = f2bf(wu1[k * 256 + c]); }
  if (i < 128 * 256) { int c = i >> 8,  k = i & 255;     wu2T[i] = f2bf(wu2[k * 128 + c]); }
}

__global__ __launch_bounds__(256) void count_k(const int* __restrict__ recv,
                                               float* __restrict__ cnts)
{
  int e = blockIdx.x * 256 + threadIdx.x;
  atomicAdd(&cnts[recv[e]], 1.0f);
}

// ------------------------------------------------------------ edge MLP ----
// 64 edges/block, 4 waves (wave tile 32 edges x 64 cols), mfma 16x16x32 bf16.
// Layer1: acc += XS@W1a + XR@W1b + EA@W1c (three K=128 sub-GEMMs).
__global__ __launch_bounds__(256) void edge_mlp(
    const u16* __restrict__ xb, const float* __restrict__ eattr,
    const int* __restrict__ send, const int* __restrict__ recv,
    const u16* __restrict__ w1T, const float* __restrict__ b1,
    const u16* __restrict__ w2T, const float* __restrict__ b2,
    float* __restrict__ msg_out, float* __restrict__ sums)
{
  __shared__ u16 sA[64][136];   // A tile, one K=128 source slice (pad 8 -> 2-way)
  __shared__ u16 sB[128][40];   // W tile col-major [col][k32] (pad -> 2-way)
  __shared__ u16 sH[64][136];   // hidden tile

  const int tid  = threadIdx.x;
  const int lane = tid & 63;
  const int wid  = tid >> 6;
  const int wr   = wid >> 1;            // edge half (32 rows)
  const int wc   = wid & 1;             // col half (64 cols)
  const int fr   = lane & 15;
  const int fk   = (lane >> 4) * 8;
  const int orow = (lane >> 4) * 4;
  const int e0   = blockIdx.x * 64;

  f32x4 acc[2][4];
  #pragma unroll
  for (int m = 0; m < 2; ++m)
    #pragma unroll
    for (int n = 0; n < 4; ++n)
      #pragma unroll
      for (int r = 0; r < 4; ++r) acc[m][n][r] = 0.f;

  // ---- layer 1 ----
  #pragma unroll 1
  for (int s = 0; s < 3; ++s) {
    // stage sA: 64 rows x 128 k (16 chunks of 8 bf16 per row)
    #pragma unroll
    for (int it = 0; it < 4; ++it) {
      int chunk = tid + it * 256;
      int e = chunk >> 4, c8 = chunk & 15;
      int ge = e0 + e;
      if (s < 2) {
        int node = (s == 0) ? send[ge] : recv[ge];
        uint4 v = *reinterpret_cast<const uint4*>(xb + (size_t)node * HID + c8 * 8);
        *reinterpret_cast<uint4*>(&sA[e][c8 * 8]) = v;
      } else {
        const float4* p = reinterpret_cast<const float4*>(eattr + (size_t)ge * HID + c8 * 8);
        float4 v0 = p[0], v1 = p[1];
        uint4 w;
        w.x = (unsigned)f2bf(v0.x) | ((unsigned)f2bf(v0.y) << 16);
        w.y = (unsigned)f2bf(v0.z) | ((unsigned)f2bf(v0.w) << 16);
        w.z = (unsigned)f2bf(v1.x) | ((unsigned)f2bf(v1.y) << 16);
        w.w = (unsigned)f2bf(v1.z) | ((unsigned)f2bf(v1.w) << 16);
        *reinterpret_cast<uint4*>(&sA[e][c8 * 8]) = w;
      }
    }
    #pragma unroll 1
    for (int kk = 0; kk < 4; ++kk) {
      #pragma unroll
      for (int it = 0; it < 2; ++it) {
        int chunk = tid + it * 256;
        int c = chunk >> 2, q = chunk & 3;
        uint4 v = *reinterpret_cast<const uint4*>(w1T + c * 384 + s * 128 + kk * 32 + q * 8);
        *reinterpret_cast<uint4*>(&sB[c][q * 8]) = v;
      }
      __syncthreads();
      bf16x8 aF[2], bF[4];
      #pragma unroll
      for (int m = 0; m < 2; ++m)
        aF[m] = __builtin_bit_cast(bf16x8,
            *reinterpret_cast<const uint4*>(&sA[wr * 32 + m * 16 + fr][kk * 32 + fk]));
      #pragma unroll
      for (int n = 0; n < 4; ++n)
        bF[n] = __builtin_bit_cast(bf16x8,
            *reinterpret_cast<const uint4*>(&sB[wc * 64 + n * 16 + fr][fk]));
      #pragma unroll
      for (int m = 0; m < 2; ++m)
        #pragma unroll
        for (int n = 0; n < 4; ++n)
          acc[m][n] = __builtin_amdgcn_mfma_f32_16x16x32_bf16(aF[m], bF[n], acc[m][n], 0, 0, 0);
      __syncthreads();
    }
  }

  // bias + SiLU -> sH (bf16), reset acc
  #pragma unroll
  for (int n = 0; n < 4; ++n) {
    int col = wc * 64 + n * 16 + fr;
    float bb = b1[col];
    #pragma unroll
    for (int m = 0; m < 2; ++m) {
      int er = wr * 32 + m * 16 + orow;
      #pragma unroll
      for (int r = 0; r < 4; ++r) {
        sH[er + r][col] = f2bf(silu_f(acc[m][n][r] + bb));
        acc[m][n][r] = 0.f;
      }
    }
  }

  // ---- layer 2 (K=128) ----
  #pragma unroll 1
  for (int kk = 0; kk < 4; ++kk) {
    #pragma unroll
    for (int it = 0; it < 2; ++it) {
      int chunk = tid + it * 256;
      int c = chunk >> 2, q = chunk & 3;
      uint4 v = *reinterpret_cast<const uint4*>(w2T + c * 128 + kk * 32 + q * 8);
      *reinterpret_cast<uint4*>(&sB[c][q * 8]) = v;
    }
    __syncthreads();
    bf16x8 aF[2], bF[4];
    #pragma unroll
    for (int m = 0; m < 2; ++m)
      aF[m] = __builtin_bit_cast(bf16x8,
          *reinterpret_cast<const uint4*>(&sH[wr * 32 + m * 16 + fr][kk * 32 + fk]));
    #pragma unroll
    for (int n = 0; n < 4; ++n)
      bF[n] = __builtin_bit_cast(bf16x8,
          *reinterpret_cast<const uint4*>(&sB[wc * 64 + n * 16 + fr][fk]));
    #pragma unroll
    for (int m = 0; m < 2; ++m)
      #pragma unroll
      for (int n = 0; n < 4; ++n)
        acc[m][n] = __builtin_amdgcn_mfma_f32_16x16x32_bf16(aF[m], bF[n], acc[m][n], 0, 0, 0);
    __syncthreads();
  }

  // epilogue: msg = silu(acc + b2) -> out + atomic scatter into sums
  #pragma unroll
  for (int m = 0; m < 2; ++m) {
    #pragma unroll
    for (int r = 0; r < 4; ++r) {
      int e = e0 + wr * 32 + m * 16 + orow + r;
      int rv = recv[e];
      #pragma unroll
      for (int n = 0; n < 4; ++n) {
        int col = wc * 64 + n * 16 + fr;
        float v = silu_f(acc[m][n][r] + b2[col]);
        msg_out[(size_t)e * HID + col] = v;
        atomicAdd(sums + (size_t)rv * HID + col, v);
      }
    }
  }
}

// ----------------------------------------------------------- node side ----
// xo_in = x + sums/max(cnt,1) -> bf16
__global__ __launch_bounds__(256) void xin_k(
    const float* __restrict__ x, const float* __restrict__ sums,
    const float* __restrict__ cnts, u16* __restrict__ xob)
{
  int idx = blockIdx.x * 256 + threadIdx.x;  // one float4 per thread, NN*HID/4
  int node = idx >> 5, q = idx & 31;
  float inv = 1.f / fmaxf(cnts[node], 1.f);
  float4 xv = reinterpret_cast<const float4*>(x)[idx];
  float4 sv = reinterpret_cast<const float4*>(sums)[idx];
  uint2 w;
  w.x = (unsigned)f2bf(xv.x + sv.x * inv) | ((unsigned)f2bf(xv.y + sv.y * inv) << 16);
  w.y = (unsigned)f2bf(xv.z + sv.z * inv) | ((unsigned)f2bf(xv.w + sv.w * inv) << 16);
  *reinterpret_cast<uint2*>(xob + (size_t)node * HID + q * 4) = w;
}

// t = silu(xo_in @ wu1 + bu1)  [NN,256]
__global__ __launch_bounds__(256) void mlp1_k(
    const u16* __restrict__ xob, const u16* __restrict__ wu1T,
    const float* __restrict__ bu1, u16* __restrict__ t)
{
  __shared__ u16 sB[256][40];
  const int tid = threadIdx.x, lane = tid & 63, wid = tid >> 6;
  const int wr = wid >> 1, wc = wid & 1;
  const int fr = lane & 15, fk = (lane >> 4) * 8, orow = (lane >> 4) * 4;
  const int n0 = blockIdx.x * 64;

  f32x4 acc[2][8];
  #pragma unroll
  for (int m = 0; m < 2; ++m)
    #pragma unroll
    for (int n = 0; n < 8; ++n)
      #pragma unroll
      for (int r = 0; r < 4; ++r) acc[m][n][r] = 0.f;

  #pragma unroll 1
  for (int kk = 0; kk < 4; ++kk) {
    #pragma unroll
    for (int it = 0; it < 4; ++it) {
      int chunk = tid + it * 256;
      int c = chunk >> 2, q = chunk & 3;
      uint4 v = *reinterpret_cast<const uint4*>(wu1T + c * 128 + kk * 32 + q * 8);
      *reinterpret_cast<uint4*>(&sB[c][q * 8]) = v;
    }
    __syncthreads();
    bf16x8 aF[2], bF[8];
    #pragma unroll
    for (int m = 0; m < 2; ++m)
      aF[m] = __builtin_bit_cast(bf16x8, *reinterpret_cast<const uint4*>(
          xob + (size_t)(n0 + wr * 32 + m * 16 + fr) * HID + kk * 32 + fk));
    #pragma unroll
    for (int n = 0; n < 8; ++n)
      bF[n] = __builtin_bit_cast(bf16x8,
          *reinterpret_cast<const uint4*>(&sB[wc * 128 + n * 16 + fr][fk]));
    #pragma unroll
    for (int m = 0; m < 2; ++m)
      #pragma unroll
      for (int n = 0; n < 8; ++n)
        acc[m][n] = __builtin_amdgcn_mfma_f32_16x16x32_bf16(aF[m], bF[n], acc[m][n], 0, 0, 0);
    __syncthreads();
  }
  #pragma unroll
  for (int n = 0; n < 8; ++n) {
    int col = wc * 128 + n * 16 + fr;
    float bb = bu1[col];
    #pragma unroll
    for (int m = 0; m < 2; ++m) {
      int row = n0 + wr * 32 + m * 16 + orow;
      #pragma unroll
      for (int r = 0; r < 4; ++r)
        t[(size_t)(row + r) * 256 + col] = f2bf(silu_f(acc[m][n][r] + bb));
    }
  }
}

// xo = xo_in + t @ wu2 + bu2
__global__ __launch_bounds__(256) void mlp2_k(
    const u16* __restrict__ t, const u16* __restrict__ wu2T,
    const float* __restrict__ bu2, const float* __restrict__ x,
    const float* __restrict__ sums, const float* __restrict__ cnts,
    float* __restrict__ xo)
{
  __shared__ u16 sB[128][40];
  const int tid = threadIdx.x, lane = tid & 63, wid = tid >> 6;
  const int wr = wid >> 1, wc = wid & 1;
  const int fr = lane & 15, fk = (lane >> 4) * 8, orow = (lane >> 4) * 4;
  const int n0 = blockIdx.x * 64;

  f32x4 acc[2][4];
  #pragma unroll
  for (int m = 0; m < 2; ++m)
    #pragma unroll
    for (int n = 0; n < 4; ++n)
      #pragma unroll
      for (int r = 0; r < 4; ++r) acc[m][n][r] = 0.f;

  #pragma unroll 1
  for (int kk = 0; kk < 8; ++kk) {
    #pragma unroll
    for (int it = 0; it < 2; ++it) {
      int chunk = tid + it * 256;
      int c = chunk >> 2, q = chunk & 3;
      uint4 v = *reinterpret_cast<const uint4*>(wu2T + c * 256 + kk * 32 + q * 8);
      *reinterpret_cast<uint4*>(&sB[c][q * 8]) = v;
    }
    __syncthreads();
    bf16x8 aF[2], bF[4];
    #pragma unroll
    for (int m = 0; m < 2; ++m)
      aF[m] = __builtin_bit_cast(bf16x8, *reinterpret_cast<const uint4*>(
          t + (size_t)(n0 + wr * 32 + m * 16 + fr) * 256 + kk * 32 + fk));
    #pragma unroll
    for (int n = 0; n < 4; ++n)
      bF[n] = __builtin_bit_cast(bf16x8,
          *reinterpret_cast<const uint4*>(&sB[wc * 64 + n * 16 + fr][fk]));
    #pragma unroll
    for (int m = 0; m < 2; ++m)
      #pragma unroll
      for (int n = 0; n < 4; ++n)
        acc[m][n] = __builtin_amdgcn_mfma_f32_16x16x32_bf16(aF[m], bF[n], acc[m][n], 0, 0, 0);
    __syncthreads();
  }
  #pragma unroll
  for (int m = 0; m < 2; ++m) {
    #pragma unroll
    for (int r = 0; r < 4; ++r) {
      int gn = n0 + wr * 32 + m * 16 + orow + r;
      float inv = 1.f / fmaxf(cnts[gn], 1.f);
      #pragma unroll
      for (int n = 0; n < 4; ++n) {
        int col = wc * 64 + n * 16 + fr;
        float xi = x[(size_t)gn * HID + col] + sums[(size_t)gn * HID + col] * inv;
        xo[(size_t)gn * HID + col] = xi + acc[m][n][r] + bu2[col];
      }
    }
  }
}

// -------------------------------------------------------------- launch ----
extern "C" void kernel_launch(void* const* d_in, const int* in_sizes, int n_in,
                              void* d_out, int out_size, void* d_ws, size_t ws_size,
                              hipStream_t stream)
{
  (void)in_sizes; (void)n_in; (void)out_size; (void)ws_size;
  const float* x     = (const float*)d_in[0];
  const float* eattr = (const float*)d_in[1];
  const int*   edges = (const int*)d_in[2];
  const float* w1  = (const float*)d_in[3];
  const float* b1  = (const float*)d_in[4];
  const float* w2  = (const float*)d_in[5];
  const float* b2  = (const float*)d_in[6];
  const float* wu1 = (const float*)d_in[7];
  const float* bu1 = (const float*)d_in[8];
  const float* wu2 = (const float*)d_in[9];
  const float* bu2 = (const float*)d_in[10];

  float* xo  = (float*)d_out;
  float* msg = xo + (size_t)NN * HID;

  char* p = (char*)d_ws;                       // ws usage ~51 MB, all 256B-aligned
  u16* xb   = (u16*)p; p += (size_t)NN * HID * 2;
  u16* w1T  = (u16*)p; p += 384 * 128 * 2;
  u16* w2T  = (u16*)p; p += 128 * 128 * 2;
  u16* wu1T = (u16*)p; p += 256 * 128 * 2;
  u16* wu2T = (u16*)p; p += 128 * 256 * 2;
  u16* xob  = (u16*)p; p += (size_t)NN * HID * 2;
  u16* tbuf = (u16*)p; p += (size_t)NN * 256 * 2;
  float* sums = (float*)p; p += (size_t)NN * HID * 4;
  float* cnts = (float*)p; p += (size_t)NN * 4;

  const int* send = edges;
  const int* recv = edges + NE;

  prep_k<<<NN * HID / 256, 256, 0, stream>>>(x, w1, w2, wu1, wu2,
                                             xb, w1T, w2T, wu1T, wu2T, sums, cnts);
  count_k<<<NE / 256, 256, 0, stream>>>(recv, cnts);
  edge_mlp<<<NE / 64, 256, 0, stream>>>(xb, eattr, send, recv,
                                        w1T, b1, w2T, b2, msg, sums);
  xin_k<<<NN * HID / 4 / 256, 256, 0, stream>>>(x, sums, cnts, xob);
  mlp1_k<<<NN / 64, 256, 0, stream>>>(xob, wu1T, bu1, tbuf);
  mlp2_k<<<NN / 64, 256, 0, stream>>>(tbuf, wu2T, bu2, x, sums, cnts, xo);
}

// Round 2
// 432.403 us; speedup vs baseline: 1.0262x; 1.0262x over previous
//
#include <hip/hip_runtime.h>
#include <hip/hip_bf16.h>

#define NN 32768
#define NE 524288
#define HID 128

typedef unsigned short u16;
typedef __bf16 bf16x8 __attribute__((ext_vector_type(8)));
typedef float f32x4 __attribute__((ext_vector_type(4)));

__device__ __forceinline__ u16 f2bf(float f) {
  union { float f; unsigned u; } v; v.f = f;
  return (u16)((v.u + 0x7fffu + ((v.u >> 16) & 1u)) >> 16);  // RNE
}
__device__ __forceinline__ float silu_f(float v) { return v / (1.f + __expf(-v)); }

// ---------------------------------------------------------------- prep ----
// zero counts, x -> bf16, weights -> bf16 transposed (col-major: wT[col][k])
__global__ __launch_bounds__(256) void prep_k(
    const float* __restrict__ x, const float* __restrict__ w1,
    const float* __restrict__ w2, const float* __restrict__ wu1,
    const float* __restrict__ wu2,
    u16* __restrict__ xb, u16* __restrict__ w1T, u16* __restrict__ w2T,
    u16* __restrict__ wu1T, u16* __restrict__ wu2T, int* __restrict__ cnt)
{
  int i = blockIdx.x * 256 + threadIdx.x;   // grid covers exactly NN*HID
  xb[i] = f2bf(x[i]);
  if (i < NN) cnt[i] = 0;
  if (i < 384 * 128) { int c = i / 384, k = i - c * 384; w1T[i]  = f2bf(w1[k * 128 + c]); }
  if (i < 128 * 128) { int c = i >> 7,  k = i & 127;     w2T[i]  = f2bf(w2[k * 128 + c]); }
  if (i < 256 * 128) { int c = i >> 7,  k = i & 127;     wu1T[i] = f2bf(wu1[k * 256 + c]); }
  if (i < 128 * 256) { int c = i >> 8,  k = i & 255;     wu2T[i] = f2bf(wu2[k * 128 + c]); }
}

__global__ __launch_bounds__(256) void count_k(const int* __restrict__ recv,
                                               int* __restrict__ cnt)
{
  int e = blockIdx.x * 256 + threadIdx.x;
  atomicAdd(&cnt[recv[e]], 1);
}

// exclusive scan of cnt[NN] -> off[NN+1]; cursor = copy of off
__global__ __launch_bounds__(1024) void scan_k(const int* __restrict__ cnt,
                                               int* __restrict__ off,
                                               int* __restrict__ cursor)
{
  __shared__ int part[1024];
  const int tid = threadIdx.x;
  const int base = tid * 32;
  int v[32];
  int s = 0;
  #pragma unroll
  for (int j = 0; j < 32; ++j) { v[j] = cnt[base + j]; s += v[j]; }
  part[tid] = s;
  __syncthreads();
  #pragma unroll 1
  for (int d = 1; d < 1024; d <<= 1) {
    int t = (tid >= d) ? part[tid - d] : 0;
    __syncthreads();
    part[tid] += t;
    __syncthreads();
  }
  int ex = part[tid] - s;   // exclusive base for this thread's chunk
  #pragma unroll
  for (int j = 0; j < 32; ++j) {
    off[base + j] = ex;
    cursor[base + j] = ex;
    ex += v[j];
  }
  if (tid == 1023) off[NN] = ex;
}

__global__ __launch_bounds__(256) void scatter_k(const int* __restrict__ recv,
                                                 int* __restrict__ cursor,
                                                 int* __restrict__ eperm)
{
  int e = blockIdx.x * 256 + threadIdx.x;
  int r = recv[e];
  int pos = atomicAdd(&cursor[r], 1);
  eperm[pos] = e;
}

// ------------------------------------------------------------ edge MLP ----
// 64 edges/block, 4 waves (wave tile 32 edges x 64 cols), mfma 16x16x32 bf16.
// Layer1: acc += XS@W1a + XR@W1b + EA@W1c; full K=128 B-panel staged per slice
// -> 32 MFMAs per barrier gap. Hidden tile reuses sA. No atomics.
__global__ __launch_bounds__(256) void edge_mlp(
    const u16* __restrict__ xb, const float* __restrict__ eattr,
    const int* __restrict__ send, const int* __restrict__ recv,
    const u16* __restrict__ w1T, const float* __restrict__ b1,
    const u16* __restrict__ w2T, const float* __restrict__ b2,
    float* __restrict__ msg_out)
{
  __shared__ u16 sA[64][136];    // A / hidden tile (pad -> 2-way, free)
  __shared__ u16 sB[128][136];   // full 128-col x 128-k W panel

  const int tid  = threadIdx.x;
  const int lane = tid & 63;
  const int wid  = tid >> 6;
  const int wr   = wid >> 1;            // edge half (32 rows)
  const int wc   = wid & 1;             // col half (64 cols)
  const int fr   = lane & 15;
  const int fk   = (lane >> 4) * 8;
  const int orow = (lane >> 4) * 4;
  const int e0   = blockIdx.x * 64;

  f32x4 acc[2][4];
  #pragma unroll
  for (int m = 0; m < 2; ++m)
    #pragma unroll
    for (int n = 0; n < 4; ++n)
      #pragma unroll
      for (int r = 0; r < 4; ++r) acc[m][n][r] = 0.f;

  // ---- layer 1: three K=128 source slices ----
  #pragma unroll 1
  for (int s = 0; s < 3; ++s) {
    #pragma unroll
    for (int it = 0; it < 4; ++it) {
      int chunk = tid + it * 256;
      int e = chunk >> 4, c8 = chunk & 15;
      int ge = e0 + e;
      if (s < 2) {
        int node = (s == 0) ? send[ge] : recv[ge];
        *reinterpret_cast<uint4*>(&sA[e][c8 * 8]) =
            *reinterpret_cast<const uint4*>(xb + (size_t)node * HID + c8 * 8);
      } else {
        const float4* p = reinterpret_cast<const float4*>(eattr + (size_t)ge * HID + c8 * 8);
        float4 v0 = p[0], v1 = p[1];
        uint4 w;
        w.x = (unsigned)f2bf(v0.x) | ((unsigned)f2bf(v0.y) << 16);
        w.y = (unsigned)f2bf(v0.z) | ((unsigned)f2bf(v0.w) << 16);
        w.z = (unsigned)f2bf(v1.x) | ((unsigned)f2bf(v1.y) << 16);
        w.w = (unsigned)f2bf(v1.z) | ((unsigned)f2bf(v1.w) << 16);
        *reinterpret_cast<uint4*>(&sA[e][c8 * 8]) = w;
      }
    }
    #pragma unroll
    for (int it = 0; it < 8; ++it) {
      int chunk = tid + it * 256;
      int c = chunk >> 4, q = chunk & 15;
      *reinterpret_cast<uint4*>(&sB[c][q * 8]) =
          *reinterpret_cast<const uint4*>(w1T + c * 384 + s * 128 + q * 8);
    }
    __syncthreads();
    #pragma unroll
    for (int kk = 0; kk < 4; ++kk) {
      bf16x8 aF[2], bF[4];
      #pragma unroll
      for (int m = 0; m < 2; ++m)
        aF[m] = __builtin_bit_cast(bf16x8,
            *reinterpret_cast<const uint4*>(&sA[wr * 32 + m * 16 + fr][kk * 32 + fk]));
      #pragma unroll
      for (int n = 0; n < 4; ++n)
        bF[n] = __builtin_bit_cast(bf16x8,
            *reinterpret_cast<const uint4*>(&sB[wc * 64 + n * 16 + fr][kk * 32 + fk]));
      #pragma unroll
      for (int m = 0; m < 2; ++m)
        #pragma unroll
        for (int n = 0; n < 4; ++n)
          acc[m][n] = __builtin_amdgcn_mfma_f32_16x16x32_bf16(aF[m], bF[n], acc[m][n], 0, 0, 0);
    }
    __syncthreads();
  }

  // hidden = silu(acc + b1) -> sA (reuse); stage w2T -> sB; reset acc
  #pragma unroll
  for (int n = 0; n < 4; ++n) {
    int col = wc * 64 + n * 16 + fr;
    float bb = b1[col];
    #pragma unroll
    for (int m = 0; m < 2; ++m) {
      int er = wr * 32 + m * 16 + orow;
      #pragma unroll
      for (int r = 0; r < 4; ++r) {
        sA[er + r][col] = f2bf(silu_f(acc[m][n][r] + bb));
        acc[m][n][r] = 0.f;
      }
    }
  }
  #pragma unroll
  for (int it = 0; it < 8; ++it) {
    int chunk = tid + it * 256;
    int c = chunk >> 4, q = chunk & 15;
    *reinterpret_cast<uint4*>(&sB[c][q * 8]) =
        *reinterpret_cast<const uint4*>(w2T + c * 128 + q * 8);
  }
  __syncthreads();

  // ---- layer 2 (K=128) ----
  #pragma unroll
  for (int kk = 0; kk < 4; ++kk) {
    bf16x8 aF[2], bF[4];
    #pragma unroll
    for (int m = 0; m < 2; ++m)
      aF[m] = __builtin_bit_cast(bf16x8,
          *reinterpret_cast<const uint4*>(&sA[wr * 32 + m * 16 + fr][kk * 32 + fk]));
    #pragma unroll
    for (int n = 0; n < 4; ++n)
      bF[n] = __builtin_bit_cast(bf16x8,
          *reinterpret_cast<const uint4*>(&sB[wc * 64 + n * 16 + fr][kk * 32 + fk]));
    #pragma unroll
    for (int m = 0; m < 2; ++m)
      #pragma unroll
      for (int n = 0; n < 4; ++n)
        acc[m][n] = __builtin_amdgcn_mfma_f32_16x16x32_bf16(aF[m], bF[n], acc[m][n], 0, 0, 0);
  }

  // epilogue: msg = silu(acc + b2) -> out (no atomics)
  #pragma unroll
  for (int m = 0; m < 2; ++m) {
    #pragma unroll
    for (int r = 0; r < 4; ++r) {
      int e = e0 + wr * 32 + m * 16 + orow + r;
      #pragma unroll
      for (int n = 0; n < 4; ++n) {
        int col = wc * 64 + n * 16 + fr;
        msg_out[(size_t)e * HID + col] = silu_f(acc[m][n][r] + b2[col]);
      }
    }
  }
}

// -------------------------------------------------------- aggregation ----
// one wave per node: gather msg rows via CSR, mean, + x -> xin (f32), xob (bf16)
__global__ __launch_bounds__(256) void agg_k(
    const float* __restrict__ msg, const int* __restrict__ off,
    const int* __restrict__ eperm, const float* __restrict__ x,
    float* __restrict__ xin, u16* __restrict__ xob)
{
  const int wid = threadIdx.x >> 6, lane = threadIdx.x & 63;
  const int n = blockIdx.x * 4 + wid;
  const int j0 = off[n], j1 = off[n + 1];
  float ax = 0.f, ay = 0.f;
  int j = j0;
  for (; j + 1 < j1; j += 2) {
    int ea = eperm[j], eb = eperm[j + 1];
    float2 va = reinterpret_cast<const float2*>(msg + (size_t)ea * HID)[lane];
    float2 vb = reinterpret_cast<const float2*>(msg + (size_t)eb * HID)[lane];
    ax += va.x + vb.x;
    ay += va.y + vb.y;
  }
  if (j < j1) {
    int ea = eperm[j];
    float2 va = reinterpret_cast<const float2*>(msg + (size_t)ea * HID)[lane];
    ax += va.x; ay += va.y;
  }
  float inv = (j1 > j0) ? 1.f / (float)(j1 - j0) : 1.f;
  float2 xv = reinterpret_cast<const float2*>(x + (size_t)n * HID)[lane];
  float x0 = xv.x + ax * inv, x1 = xv.y + ay * inv;
  reinterpret_cast<float2*>(xin + (size_t)n * HID)[lane] = make_float2(x0, x1);
  reinterpret_cast<unsigned*>(xob)[n * 64 + lane] =
      (unsigned)f2bf(x0) | ((unsigned)f2bf(x1) << 16);
}

// ----------------------------------------------------------- update MLP ----
// t = silu(xin @ wu1 + bu1)  [NN,256]
__global__ __launch_bounds__(256) void mlp1_k(
    const u16* __restrict__ xob, const u16* __restrict__ wu1T,
    const float* __restrict__ bu1, u16* __restrict__ t)
{
  __shared__ u16 sB[256][40];
  const int tid = threadIdx.x, lane = tid & 63, wid = tid >> 6;
  const int wr = wid >> 1, wc = wid & 1;
  const int fr = lane & 15, fk = (lane >> 4) * 8, orow = (lane >> 4) * 4;
  const int n0 = blockIdx.x * 64;

  f32x4 acc[2][8];
  #pragma unroll
  for (int m = 0; m < 2; ++m)
    #pragma unroll
    for (int n = 0; n < 8; ++n)
      #pragma unroll
      for (int r = 0; r < 4; ++r) acc[m][n][r] = 0.f;

  #pragma unroll 1
  for (int kk = 0; kk < 4; ++kk) {
    #pragma unroll
    for (int it = 0; it < 4; ++it) {
      int chunk = tid + it * 256;
      int c = chunk >> 2, q = chunk & 3;
      *reinterpret_cast<uint4*>(&sB[c][q * 8]) =
          *reinterpret_cast<const uint4*>(wu1T + c * 128 + kk * 32 + q * 8);
    }
    __syncthreads();
    bf16x8 aF[2], bF[8];
    #pragma unroll
    for (int m = 0; m < 2; ++m)
      aF[m] = __builtin_bit_cast(bf16x8, *reinterpret_cast<const uint4*>(
          xob + (size_t)(n0 + wr * 32 + m * 16 + fr) * HID + kk * 32 + fk));
    #pragma unroll
    for (int n = 0; n < 8; ++n)
      bF[n] = __builtin_bit_cast(bf16x8,
          *reinterpret_cast<const uint4*>(&sB[wc * 128 + n * 16 + fr][fk]));
    #pragma unroll
    for (int m = 0; m < 2; ++m)
      #pragma unroll
      for (int n = 0; n < 8; ++n)
        acc[m][n] = __builtin_amdgcn_mfma_f32_16x16x32_bf16(aF[m], bF[n], acc[m][n], 0, 0, 0);
    __syncthreads();
  }
  #pragma unroll
  for (int n = 0; n < 8; ++n) {
    int col = wc * 128 + n * 16 + fr;
    float bb = bu1[col];
    #pragma unroll
    for (int m = 0; m < 2; ++m) {
      int row = n0 + wr * 32 + m * 16 + orow;
      #pragma unroll
      for (int r = 0; r < 4; ++r)
        t[(size_t)(row + r) * 256 + col] = f2bf(silu_f(acc[m][n][r] + bb));
    }
  }
}

// xo = xin + t @ wu2 + bu2
__global__ __launch_bounds__(256) void mlp2_k(
    const u16* __restrict__ t, const u16* __restrict__ wu2T,
    const float* __restrict__ bu2, const float* __restrict__ xin,
    float* __restrict__ xo)
{
  __shared__ u16 sB[128][40];
  const int tid = threadIdx.x, lane = tid & 63, wid = tid >> 6;
  const int wr = wid >> 1, wc = wid & 1;
  const int fr = lane & 15, fk = (lane >> 4) * 8, orow = (lane >> 4) * 4;
  const int n0 = blockIdx.x * 64;

  f32x4 acc[2][4];
  #pragma unroll
  for (int m = 0; m < 2; ++m)
    #pragma unroll
    for (int n = 0; n < 4; ++n)
      #pragma unroll
      for (int r = 0; r < 4; ++r) acc[m][n][r] = 0.f;

  #pragma unroll 1
  for (int kk = 0; kk < 8; ++kk) {
    #pragma unroll
    for (int it = 0; it < 2; ++it) {
      int chunk = tid + it * 256;
      int c = chunk >> 2, q = chunk & 3;
      *reinterpret_cast<uint4*>(&sB[c][q * 8]) =
          *reinterpret_cast<const uint4*>(wu2T + c * 256 + kk * 32 + q * 8);
    }
    __syncthreads();
    bf16x8 aF[2], bF[4];
    #pragma unroll
    for (int m = 0; m < 2; ++m)
      aF[m] = __builtin_bit_cast(bf16x8, *reinterpret_cast<const uint4*>(
          t + (size_t)(n0 + wr * 32 + m * 16 + fr) * 256 + kk * 32 + fk));
    #pragma unroll
    for (int n = 0; n < 4; ++n)
      bF[n] = __builtin_bit_cast(bf16x8,
          *reinterpret_cast<const uint4*>(&sB[wc * 64 + n * 16 + fr][fk]));
    #pragma unroll
    for (int m = 0; m < 2; ++m)
      #pragma unroll
      for (int n = 0; n < 4; ++n)
        acc[m][n] = __builtin_amdgcn_mfma_f32_16x16x32_bf16(aF[m], bF[n], acc[m][n], 0, 0, 0);
    __syncthreads();
  }
  #pragma unroll
  for (int m = 0; m < 2; ++m) {
    #pragma unroll
    for (int r = 0; r < 4; ++r) {
      int gn = n0 + wr * 32 + m * 16 + orow + r;
      #pragma unroll
      for (int n = 0; n < 4; ++n) {
        int col = wc * 64 + n * 16 + fr;
        xo[(size_t)gn * HID + col] =
            xin[(size_t)gn * HID + col] + acc[m][n][r] + bu2[col];
      }
    }
  }
}

// -------------------------------------------------------------- launch ----
extern "C" void kernel_launch(void* const* d_in, const int* in_sizes, int n_in,
                              void* d_out, int out_size, void* d_ws, size_t ws_size,
                              hipStream_t stream)
{
  (void)in_sizes; (void)n_in; (void)out_size; (void)ws_size;
  const float* x     = (const float*)d_in[0];
  const float* eattr = (const float*)d_in[1];
  const int*   edges = (const int*)d_in[2];
  const float* w1  = (const float*)d_in[3];
  const float* b1  = (const float*)d_in[4];
  const float* w2  = (const float*)d_in[5];
  const float* b2  = (const float*)d_in[6];
  const float* wu1 = (const float*)d_in[7];
  const float* bu1 = (const float*)d_in[8];
  const float* wu2 = (const float*)d_in[9];
  const float* bu2 = (const float*)d_in[10];

  float* xo  = (float*)d_out;
  float* msg = xo + (size_t)NN * HID;

  char* p = (char*)d_ws;                       // ~53 MB total
  u16* xb   = (u16*)p; p += (size_t)NN * HID * 2;
  u16* w1T  = (u16*)p; p += 384 * 128 * 2;
  u16* w2T  = (u16*)p; p += 128 * 128 * 2;
  u16* wu1T = (u16*)p; p += 256 * 128 * 2;
  u16* wu2T = (u16*)p; p += 128 * 256 * 2;
  u16* xob  = (u16*)p; p += (size_t)NN * HID * 2;
  u16* tbuf = (u16*)p; p += (size_t)NN * 256 * 2;
  float* xin = (float*)p; p += (size_t)NN * HID * 4;
  int* cnt    = (int*)p; p += (size_t)NN * 4;
  int* off    = (int*)p; p += (size_t)(NN + 64) * 4;
  int* cursor = (int*)p; p += (size_t)NN * 4;
  int* eperm  = (int*)p; p += (size_t)NE * 4;

  const int* send = edges;
  const int* recv = edges + NE;

  prep_k<<<NN * HID / 256, 256, 0, stream>>>(x, w1, w2, wu1, wu2,
                                             xb, w1T, w2T, wu1T, wu2T, cnt);
  count_k<<<NE / 256, 256, 0, stream>>>(recv, cnt);
  scan_k<<<1, 1024, 0, stream>>>(cnt, off, cursor);
  scatter_k<<<NE / 256, 256, 0, stream>>>(recv, cursor, eperm);
  edge_mlp<<<NE / 64, 256, 0, stream>>>(xb, eattr, send, recv,
                                        w1T, b1, w2T, b2, msg);
  agg_k<<<NN / 4, 256, 0, stream>>>(msg, off, eperm, x, xin, xob);
  mlp1_k<<<NN / 64, 256, 0, stream>>>(xob, wu1T, bu1, tbuf);
  mlp2_k<<<NN / 64, 256, 0, stream>>>(tbuf, wu2T, bu2, xin, xo);
}

// Round 3
// 339.442 us; speedup vs baseline: 1.3072x; 1.2739x over previous
//
#include <hip/hip_runtime.h>
#include <hip/hip_bf16.h>

#define NN 32768
#define NE 524288
#define HID 128

typedef unsigned short u16;
typedef unsigned int u32;
typedef __bf16 bf16x8 __attribute__((ext_vector_type(8)));
typedef float f32x4 __attribute__((ext_vector_type(4)));

__device__ __forceinline__ u16 f2bf(float f) {
  union { float f; unsigned u; } v; v.f = f;
  return (u16)((v.u + 0x7fffu + ((v.u >> 16) & 1u)) >> 16);  // RNE
}
__device__ __forceinline__ float silu_f(float v) {
  return v * __builtin_amdgcn_rcpf(1.f + __expf(-v));
}

// async global->LDS, 16B per lane. LDS dest: wave-uniform base + lane*16.
__device__ __forceinline__ void gld16(const void* g, void* l) {
  __builtin_amdgcn_global_load_lds(
      (const __attribute__((address_space(1))) u32*)g,
      (__attribute__((address_space(3))) u32*)l, 16, 0, 0);
}

// ---------------------------------------------------------------- prep ----
// zero counts, x -> bf16, weights -> bf16.
// w1Ts/w2Ts: col-major AND chunk-XOR-swizzled (16B chunk q at position
// q^(c&7) within row c) so a linear global_load_lds lands them swizzled.
// wu1T/wu2T: plain col-major (padded-LDS path in mlp kernels).
__global__ __launch_bounds__(256) void prep_k(
    const float* __restrict__ x, const float* __restrict__ w1,
    const float* __restrict__ w2, const float* __restrict__ wu1,
    const float* __restrict__ wu2,
    u16* __restrict__ xb, u16* __restrict__ w1Ts, u16* __restrict__ w2Ts,
    u16* __restrict__ wu1T, u16* __restrict__ wu2T, int* __restrict__ cnt)
{
  int i = blockIdx.x * 256 + threadIdx.x;   // grid covers exactly NN*HID
  xb[i] = f2bf(x[i]);
  if (i < NN) cnt[i] = 0;
  if (i < 3 * 128 * 128) {                  // w1Ts [s][c][q^(c&7)][j]
    int j = i & 7, qs = (i >> 3) & 15, c = (i >> 7) & 127, s = i >> 14;
    int k = s * 128 + ((qs ^ (c & 7)) << 3) + j;
    w1Ts[i] = f2bf(w1[k * 128 + c]);
  }
  if (i < 128 * 128) {                      // w2Ts [c][q^(c&7)][j]
    int j = i & 7, qs = (i >> 3) & 15, c = i >> 7;
    int k = ((qs ^ (c & 7)) << 3) + j;
    w2Ts[i] = f2bf(w2[k * 128 + c]);
  }
  if (i < 256 * 128) { int c = i >> 7, k = i & 127; wu1T[i] = f2bf(wu1[k * 256 + c]); }
  if (i < 128 * 256) { int c = i >> 8, k = i & 255; wu2T[i] = f2bf(wu2[k * 128 + c]); }
}

__global__ __launch_bounds__(256) void count_k(const int* __restrict__ recv,
                                               int* __restrict__ cnt)
{
  int e = blockIdx.x * 256 + threadIdx.x;
  atomicAdd(&cnt[recv[e]], 1);
}

// exclusive scan of cnt[NN] -> off[NN+1]; cursor = copy of off
__global__ __launch_bounds__(1024) void scan_k(const int* __restrict__ cnt,
                                               int* __restrict__ off,
                                               int* __restrict__ cursor)
{
  __shared__ int part[1024];
  const int tid = threadIdx.x;
  const int base = tid * 32;
  int v[32];
  int s = 0;
  #pragma unroll
  for (int j = 0; j < 32; ++j) { v[j] = cnt[base + j]; s += v[j]; }
  part[tid] = s;
  __syncthreads();
  #pragma unroll 1
  for (int d = 1; d < 1024; d <<= 1) {
    int t = (tid >= d) ? part[tid - d] : 0;
    __syncthreads();
    part[tid] += t;
    __syncthreads();
  }
  int ex = part[tid] - s;
  #pragma unroll
  for (int j = 0; j < 32; ++j) {
    off[base + j] = ex;
    cursor[base + j] = ex;
    ex += v[j];
  }
  if (tid == 1023) off[NN] = ex;
}

__global__ __launch_bounds__(256) void scatter_k(const int* __restrict__ recv,
                                                 int* __restrict__ cursor,
                                                 int* __restrict__ eperm)
{
  int e = blockIdx.x * 256 + threadIdx.x;
  int r = recv[e];
  int pos = atomicAdd(&cursor[r], 1);
  eperm[pos] = e;
}

// ------------------------------------------------------------ edge MLP ----
// 128 edges/block, 8 waves (4x2 grid of 32x64 wave tiles), mfma 16x16x32.
// LDS unpadded [128][128] bf16 with 16B-chunk XOR swizzle (chunk ^= row&7):
//  - x gathers:   global_load_lds, per-lane source pre-swizzled
//  - weights:     global_load_lds, linear copy of pre-swizzled w1Ts/w2Ts
//  - eattr slice: register staging + f2bf + swizzled ds_write_b128
// Fragment ds_read_b128 on swizzled layout is <=2-way bank aliased (free).
__global__ __launch_bounds__(512, 4) void edge_mlp(
    const u16* __restrict__ xb, const float* __restrict__ eattr,
    const int* __restrict__ send, const int* __restrict__ recv,
    const u16* __restrict__ w1Ts, const float* __restrict__ b1,
    const u16* __restrict__ w2Ts, const float* __restrict__ b2,
    float* __restrict__ msg_out)
{
  __shared__ u16 sA[128 * 128];
  __shared__ u16 sB[128 * 128];

  const int tid  = threadIdx.x;
  const int lane = tid & 63;
  const int w    = tid >> 6;
  const int wr   = w >> 1;              // 0..3: 32-edge stripe
  const int wc   = w & 1;               // 0..1: 64-col half
  const int fr   = lane & 15;
  const int fkq  = lane >> 4;           // k-quarter within fragment
  const int orow = fkq * 4;
  const int e0   = blockIdx.x * 128;

  const int lrow4 = lane >> 4;          // row within 4-row staging group
  const int schk  = lane & 15;          // linear LDS chunk this lane fills

  // prefetch node ids for this wave's 16 staging rows
  int nds[4], ndr[4];
  #pragma unroll
  for (int i = 0; i < 4; ++i) {
    int e = e0 + w * 16 + i * 4 + lrow4;
    nds[i] = send[e];
    ndr[i] = recv[e];
  }

  f32x4 acc[2][4];
  #pragma unroll
  for (int m = 0; m < 2; ++m)
    #pragma unroll
    for (int n = 0; n < 4; ++n)
      #pragma unroll
      for (int r = 0; r < 4; ++r) acc[m][n][r] = 0.f;

  // ---- layer 1: three K=128 source slices ----
  #pragma unroll
  for (int s = 0; s < 3; ++s) {
    if (s < 2) {
      #pragma unroll
      for (int i = 0; i < 4; ++i) {
        int rloc = w * 16 + i * 4 + lrow4;
        int node = (s == 0) ? nds[i] : ndr[i];
        gld16(xb + ((size_t)node << 7) + ((schk ^ (rloc & 7)) << 3),
              sA + ((w * 16 + i * 4) << 7));
      }
    } else {
      #pragma unroll
      for (int i = 0; i < 4; ++i) {
        int rloc = w * 16 + i * 4 + lrow4;
        int gchk = schk ^ (rloc & 7);
        const float4* p = reinterpret_cast<const float4*>(
            eattr + ((size_t)(e0 + rloc) << 7) + (gchk << 3));
        float4 v0 = p[0], v1 = p[1];
        uint4 d;
        d.x = (unsigned)f2bf(v0.x) | ((unsigned)f2bf(v0.y) << 16);
        d.y = (unsigned)f2bf(v0.z) | ((unsigned)f2bf(v0.w) << 16);
        d.z = (unsigned)f2bf(v1.x) | ((unsigned)f2bf(v1.y) << 16);
        d.w = (unsigned)f2bf(v1.z) | ((unsigned)f2bf(v1.w) << 16);
        *reinterpret_cast<uint4*>(sA + (rloc << 7) + (schk << 3)) = d;
      }
    }
    #pragma unroll
    for (int i = 0; i < 4; ++i) {
      gld16(w1Ts + ((size_t)s << 14) + ((w * 16 + i * 4) << 7) + (lane << 3),
            sB + ((w * 16 + i * 4) << 7));
    }
    __syncthreads();
    #pragma unroll
    for (int kk = 0; kk < 4; ++kk) {
      bf16x8 aF[2], bF[4];
      #pragma unroll
      for (int m = 0; m < 2; ++m) {
        int row = wr * 32 + m * 16 + fr;
        int ch = (kk * 4 + fkq) ^ (row & 7);
        aF[m] = __builtin_bit_cast(bf16x8,
            *reinterpret_cast<const uint4*>(sA + (row << 7) + (ch << 3)));
      }
      #pragma unroll
      for (int n = 0; n < 4; ++n) {
        int c = wc * 64 + n * 16 + fr;
        int ch = (kk * 4 + fkq) ^ (c & 7);
        bF[n] = __builtin_bit_cast(bf16x8,
            *reinterpret_cast<const uint4*>(sB + (c << 7) + (ch << 3)));
      }
      #pragma unroll
      for (int m = 0; m < 2; ++m)
        #pragma unroll
        for (int n = 0; n < 4; ++n)
          acc[m][n] = __builtin_amdgcn_mfma_f32_16x16x32_bf16(aF[m], bF[n], acc[m][n], 0, 0, 0);
    }
    __syncthreads();
  }

  // hidden = silu(acc + b1) -> sA (swizzled scalar writes); stage w2Ts -> sB
  #pragma unroll
  for (int n = 0; n < 4; ++n) {
    int c = wc * 64 + n * 16 + fr;
    float bb = b1[c];
    #pragma unroll
    for (int m = 0; m < 2; ++m) {
      #pragma unroll
      for (int r = 0; r < 4; ++r) {
        int row = wr * 32 + m * 16 + orow + r;
        sA[(row << 7) + (((c >> 3) ^ (row & 7)) << 3) + (c & 7)] =
            f2bf(silu_f(acc[m][n][r] + bb));
        acc[m][n][r] = 0.f;
      }
    }
  }
  #pragma unroll
  for (int i = 0; i < 4; ++i) {
    gld16(w2Ts + ((w * 16 + i * 4) << 7) + (lane << 3),
          sB + ((w * 16 + i * 4) << 7));
  }
  __syncthreads();

  // ---- layer 2 (K=128) ----
  #pragma unroll
  for (int kk = 0; kk < 4; ++kk) {
    bf16x8 aF[2], bF[4];
    #pragma unroll
    for (int m = 0; m < 2; ++m) {
      int row = wr * 32 + m * 16 + fr;
      int ch = (kk * 4 + fkq) ^ (row & 7);
      aF[m] = __builtin_bit_cast(bf16x8,
          *reinterpret_cast<const uint4*>(sA + (row << 7) + (ch << 3)));
    }
    #pragma unroll
    for (int n = 0; n < 4; ++n) {
      int c = wc * 64 + n * 16 + fr;
      int ch = (kk * 4 + fkq) ^ (c & 7);
      bF[n] = __builtin_bit_cast(bf16x8,
          *reinterpret_cast<const uint4*>(sB + (c << 7) + (ch << 3)));
    }
    #pragma unroll
    for (int m = 0; m < 2; ++m)
      #pragma unroll
      for (int n = 0; n < 4; ++n)
        acc[m][n] = __builtin_amdgcn_mfma_f32_16x16x32_bf16(aF[m], bF[n], acc[m][n], 0, 0, 0);
  }

  // epilogue: msg = silu(acc + b2)
  #pragma unroll
  for (int m = 0; m < 2; ++m) {
    #pragma unroll
    for (int r = 0; r < 4; ++r) {
      int e = e0 + wr * 32 + m * 16 + orow + r;
      #pragma unroll
      for (int n = 0; n < 4; ++n) {
        int c = wc * 64 + n * 16 + fr;
        msg_out[(size_t)e * HID + c] = silu_f(acc[m][n][r] + b2[c]);
      }
    }
  }
}

// -------------------------------------------------------- aggregation ----
// one wave per node: gather msg rows via CSR, mean, + x -> xin (f32), xob (bf16)
__global__ __launch_bounds__(256) void agg_k(
    const float* __restrict__ msg, const int* __restrict__ off,
    const int* __restrict__ eperm, const float* __restrict__ x,
    float* __restrict__ xin, u16* __restrict__ xob)
{
  const int wid = threadIdx.x >> 6, lane = threadIdx.x & 63;
  const int n = blockIdx.x * 4 + wid;
  const int j0 = off[n], j1 = off[n + 1];
  float ax = 0.f, ay = 0.f;
  int j = j0;
  for (; j + 1 < j1; j += 2) {
    int ea = eperm[j], eb = eperm[j + 1];
    float2 va = reinterpret_cast<const float2*>(msg + (size_t)ea * HID)[lane];
    float2 vb = reinterpret_cast<const float2*>(msg + (size_t)eb * HID)[lane];
    ax += va.x + vb.x;
    ay += va.y + vb.y;
  }
  if (j < j1) {
    int ea = eperm[j];
    float2 va = reinterpret_cast<const float2*>(msg + (size_t)ea * HID)[lane];
    ax += va.x; ay += va.y;
  }
  float inv = (j1 > j0) ? 1.f / (float)(j1 - j0) : 1.f;
  float2 xv = reinterpret_cast<const float2*>(x + (size_t)n * HID)[lane];
  float x0 = xv.x + ax * inv, x1 = xv.y + ay * inv;
  reinterpret_cast<float2*>(xin + (size_t)n * HID)[lane] = make_float2(x0, x1);
  reinterpret_cast<unsigned*>(xob)[n * 64 + lane] =
      (unsigned)f2bf(x0) | ((unsigned)f2bf(x1) << 16);
}

// ----------------------------------------------------------- update MLP ----
// t = silu(xin @ wu1 + bu1)  [NN,256]
__global__ __launch_bounds__(256) void mlp1_k(
    const u16* __restrict__ xob, const u16* __restrict__ wu1T,
    const float* __restrict__ bu1, u16* __restrict__ t)
{
  __shared__ u16 sB[256][40];
  const int tid = threadIdx.x, lane = tid & 63, wid = tid >> 6;
  const int wr = wid >> 1, wc = wid & 1;
  const int fr = lane & 15, fk = (lane >> 4) * 8, orow = (lane >> 4) * 4;
  const int n0 = blockIdx.x * 64;

  f32x4 acc[2][8];
  #pragma unroll
  for (int m = 0; m < 2; ++m)
    #pragma unroll
    for (int n = 0; n < 8; ++n)
      #pragma unroll
      for (int r = 0; r < 4; ++r) acc[m][n][r] = 0.f;

  #pragma unroll 1
  for (int kk = 0; kk < 4; ++kk) {
    #pragma unroll
    for (int it = 0; it < 4; ++it) {
      int chunk = tid + it * 256;
      int c = chunk >> 2, q = chunk & 3;
      *reinterpret_cast<uint4*>(&sB[c][q * 8]) =
          *reinterpret_cast<const uint4*>(wu1T + c * 128 + kk * 32 + q * 8);
    }
    __syncthreads();
    bf16x8 aF[2], bF[8];
    #pragma unroll
    for (int m = 0; m < 2; ++m)
      aF[m] = __builtin_bit_cast(bf16x8, *reinterpret_cast<const uint4*>(
          xob + (size_t)(n0 + wr * 32 + m * 16 + fr) * HID + kk * 32 + fk));
    #pragma unroll
    for (int n = 0; n < 8; ++n)
      bF[n] = __builtin_bit_cast(bf16x8,
          *reinterpret_cast<const uint4*>(&sB[wc * 128 + n * 16 + fr][fk]));
    #pragma unroll
    for (int m = 0; m < 2; ++m)
      #pragma unroll
      for (int n = 0; n < 8; ++n)
        acc[m][n] = __builtin_amdgcn_mfma_f32_16x16x32_bf16(aF[m], bF[n], acc[m][n], 0, 0, 0);
    __syncthreads();
  }
  #pragma unroll
  for (int n = 0; n < 8; ++n) {
    int col = wc * 128 + n * 16 + fr;
    float bb = bu1[col];
    #pragma unroll
    for (int m = 0; m < 2; ++m) {
      int row = n0 + wr * 32 + m * 16 + orow;
      #pragma unroll
      for (int r = 0; r < 4; ++r)
        t[(size_t)(row + r) * 256 + col] = f2bf(silu_f(acc[m][n][r] + bb));
    }
  }
}

// xo = xin + t @ wu2 + bu2
__global__ __launch_bounds__(256) void mlp2_k(
    const u16* __restrict__ t, const u16* __restrict__ wu2T,
    const float* __restrict__ bu2, const float* __restrict__ xin,
    float* __restrict__ xo)
{
  __shared__ u16 sB[128][40];
  const int tid = threadIdx.x, lane = tid & 63, wid = tid >> 6;
  const int wr = wid >> 1, wc = wid & 1;
  const int fr = lane & 15, fk = (lane >> 4) * 8, orow = (lane >> 4) * 4;
  const int n0 = blockIdx.x * 64;

  f32x4 acc[2][4];
  #pragma unroll
  for (int m = 0; m < 2; ++m)
    #pragma unroll
    for (int n = 0; n < 4; ++n)
      #pragma unroll
      for (int r = 0; r < 4; ++r) acc[m][n][r] = 0.f;

  #pragma unroll 1
  for (int kk = 0; kk < 8; ++kk) {
    #pragma unroll
    for (int it = 0; it < 2; ++it) {
      int chunk = tid + it * 256;
      int c = chunk >> 2, q = chunk & 3;
      *reinterpret_cast<uint4*>(&sB[c][q * 8]) =
          *reinterpret_cast<const uint4*>(wu2T + c * 256 + kk * 32 + q * 8);
    }
    __syncthreads();
    bf16x8 aF[2], bF[4];
    #pragma unroll
    for (int m = 0; m < 2; ++m)
      aF[m] = __builtin_bit_cast(bf16x8, *reinterpret_cast<const uint4*>(
          t + (size_t)(n0 + wr * 32 + m * 16 + fr) * 256 + kk * 32 + fk));
    #pragma unroll
    for (int n = 0; n < 4; ++n)
      bF[n] = __builtin_bit_cast(bf16x8,
          *reinterpret_cast<const uint4*>(&sB[wc * 64 + n * 16 + fr][fk]));
    #pragma unroll
    for (int m = 0; m < 2; ++m)
      #pragma unroll
      for (int n = 0; n < 4; ++n)
        acc[m][n] = __builtin_amdgcn_mfma_f32_16x16x32_bf16(aF[m], bF[n], acc[m][n], 0, 0, 0);
    __syncthreads();
  }
  #pragma unroll
  for (int m = 0; m < 2; ++m) {
    #pragma unroll
    for (int r = 0; r < 4; ++r) {
      int gn = n0 + wr * 32 + m * 16 + orow + r;
      #pragma unroll
      for (int n = 0; n < 4; ++n) {
        int col = wc * 64 + n * 16 + fr;
        xo[(size_t)gn * HID + col] =
            xin[(size_t)gn * HID + col] + acc[m][n][r] + bu2[col];
      }
    }
  }
}

// -------------------------------------------------------------- launch ----
extern "C" void kernel_launch(void* const* d_in, const int* in_sizes, int n_in,
                              void* d_out, int out_size, void* d_ws, size_t ws_size,
                              hipStream_t stream)
{
  (void)in_sizes; (void)n_in; (void)out_size; (void)ws_size;
  const float* x     = (const float*)d_in[0];
  const float* eattr = (const float*)d_in[1];
  const int*   edges = (const int*)d_in[2];
  const float* w1  = (const float*)d_in[3];
  const float* b1  = (const float*)d_in[4];
  const float* w2  = (const float*)d_in[5];
  const float* b2  = (const float*)d_in[6];
  const float* wu1 = (const float*)d_in[7];
  const float* bu1 = (const float*)d_in[8];
  const float* wu2 = (const float*)d_in[9];
  const float* bu2 = (const float*)d_in[10];

  float* xo  = (float*)d_out;
  float* msg = xo + (size_t)NN * HID;

  char* p = (char*)d_ws;                       // ~53 MB total
  u16* xb    = (u16*)p; p += (size_t)NN * HID * 2;
  u16* w1Ts  = (u16*)p; p += 384 * 128 * 2;
  u16* w2Ts  = (u16*)p; p += 128 * 128 * 2;
  u16* wu1T  = (u16*)p; p += 256 * 128 * 2;
  u16* wu2T  = (u16*)p; p += 128 * 256 * 2;
  u16* xob   = (u16*)p; p += (size_t)NN * HID * 2;
  u16* tbuf  = (u16*)p; p += (size_t)NN * 256 * 2;
  float* xin = (float*)p; p += (size_t)NN * HID * 4;
  int* cnt    = (int*)p; p += (size_t)NN * 4;
  int* off    = (int*)p; p += (size_t)(NN + 64) * 4;
  int* cursor = (int*)p; p += (size_t)NN * 4;
  int* eperm  = (int*)p; p += (size_t)NE * 4;

  const int* send = edges;
  const int* recv = edges + NE;

  prep_k<<<NN * HID / 256, 256, 0, stream>>>(x, w1, w2, wu1, wu2,
                                             xb, w1Ts, w2Ts, wu1T, wu2T, cnt);
  count_k<<<NE / 256, 256, 0, stream>>>(recv, cnt);
  scan_k<<<1, 1024, 0, stream>>>(cnt, off, cursor);
  scatter_k<<<NE / 256, 256, 0, stream>>>(recv, cursor, eperm);
  edge_mlp<<<NE / 128, 512, 0, stream>>>(xb, eattr, send, recv,
                                         w1Ts, b1, w2Ts, b2, msg);
  agg_k<<<NN / 4, 256, 0, stream>>>(msg, off, eperm, x, xin, xob);
  mlp1_k<<<NN / 64, 256, 0, stream>>>(xob, wu1T, bu1, tbuf);
  mlp2_k<<<NN / 64, 256, 0, stream>>>(tbuf, wu2T, bu2, xin, xo);
}